// Round 1
// baseline (416.970 us; speedup 1.0000x reference)
//
#include <hip/hip_runtime.h>
#include <hip/hip_bf16.h>

#define NN_NODES 10000
#define HID 256
#define BN_EPS 1e-5f

typedef __bf16 bf16x4 __attribute__((ext_vector_type(4)));
typedef __bf16 bf16x8 __attribute__((ext_vector_type(8)));
typedef float f32x4 __attribute__((ext_vector_type(4)));

// ------------------------------------------------------------------
// Edge-layout detection: if edge_index is int64, reading as int32 gives
// (value, 0) pairs -> all odd words zero (values in [0,10000)).
__global__ void detect_i64(const int* __restrict__ e, unsigned* __restrict__ flag) {
    __shared__ int any_nonzero;
    if (threadIdx.x == 0) any_nonzero = 0;
    __syncthreads();
    int v = e[2 * threadIdx.x + 1];
    if (v != 0) any_nonzero = 1;
    __syncthreads();
    if (threadIdx.x == 0) *flag = (any_nonzero == 0) ? 1u : 0u;  // 1 => int64 layout
}

__device__ __forceinline__ int edge_val(const int* e, unsigned f, long idx) {
    return f ? e[2 * idx] : e[idx];
}

__global__ void zero_u32(unsigned* p, int n) {
    int i = blockIdx.x * blockDim.x + threadIdx.x;
    if (i < n) p[i] = 0u;
}

__global__ void count_edges(const int* __restrict__ e, const unsigned* __restrict__ flag,
                            unsigned* __restrict__ cnt, int E) {
    int i = blockIdx.x * blockDim.x + threadIdx.x;
    if (i >= E) return;
    unsigned f = *flag;
    int dst = edge_val(e, f, (long)E + i);
    atomicAdd(&cnt[dst], 1u);
}

__global__ void compute_dinv(const unsigned* __restrict__ cnt, float* __restrict__ dinv, int n) {
    int i = blockIdx.x * blockDim.x + threadIdx.x;
    if (i < n) dinv[i] = rsqrtf((float)cnt[i] + 1.0f);
}

// Single-block exclusive scan over n counts -> off[0..n], cur = copy of off[0..n-1]
__global__ void scan_offsets(const unsigned* __restrict__ cnt, unsigned* __restrict__ off,
                             unsigned* __restrict__ cur, int n) {
    __shared__ unsigned partial[256];
    int t = threadIdx.x;
    int chunk = (n + 255) / 256;
    int lo = t * chunk;
    int hi = lo + chunk; if (hi > n) hi = n; if (lo > n) lo = n;
    unsigned s = 0;
    for (int i = lo; i < hi; ++i) s += cnt[i];
    partial[t] = s;
    __syncthreads();
    for (int d = 1; d < 256; d <<= 1) {
        unsigned v = (t >= d) ? partial[t - d] : 0u;
        __syncthreads();
        partial[t] += v;
        __syncthreads();
    }
    unsigned base = (t == 0) ? 0u : partial[t - 1];
    for (int i = lo; i < hi; ++i) {
        off[i] = base; cur[i] = base;
        base += cnt[i];
    }
    if (t == 255) off[n] = base;
}

__global__ void fill_csr(const int* __restrict__ e, const unsigned* __restrict__ flag,
                         unsigned* __restrict__ cur, int* __restrict__ csr_src, int E) {
    int i = blockIdx.x * blockDim.x + threadIdx.x;
    if (i >= E) return;
    unsigned f = *flag;
    int src = edge_val(e, f, (long)i);
    int dst = edge_val(e, f, (long)E + i);
    unsigned pos = atomicAdd(&cur[dst], 1u);
    csr_src[pos] = src;
}

// ------------------------------------------------------------------
// Split-bf16 MFMA GEMM:  C(MxN) = A(MxK,f32) * B^T   (B given as NxK, f32)
// Each fp32 is split hi+lo bf16; 3 MFMAs recover ~fp32 accuracy.
#define BM 64
#define BN 64
#define BK 32
#define LDSP 40  // padded LDS row stride (bf16 elems) to break bank conflicts

__global__ __launch_bounds__(256) void gemm_bt(
    const float* __restrict__ A, const float* __restrict__ B,
    const float* __restrict__ bias, float* __restrict__ C,
    int M, int N, int K, int doRelu)
{
    __shared__ __align__(16) __bf16 Ah[BM][LDSP];
    __shared__ __align__(16) __bf16 Al[BM][LDSP];
    __shared__ __align__(16) __bf16 Bh[BN][LDSP];
    __shared__ __align__(16) __bf16 Bl[BN][LDSP];

    const int tid  = threadIdx.x;
    const int bm   = blockIdx.x * BM;
    const int bn   = blockIdx.y * BN;
    const int wid  = tid >> 6;
    const int lane = tid & 63;
    const int wr   = wid >> 1;   // 0..1: M half
    const int wc   = wid & 1;    // 0..1: N half
    const int fr   = lane & 15;
    const int fq   = lane >> 4;

    f32x4 acc[2][2] = {};

    const int rs = tid >> 3;          // 0..31
    const int cs = (tid & 7) << 2;    // 0..28 step 4

    for (int k0 = 0; k0 < K; k0 += BK) {
#pragma unroll
        for (int it = 0; it < 2; ++it) {
            int r = rs + it * 32;
            int gr = bm + r; if (gr >= M) gr = M - 1;
            float4 v = *(const float4*)(A + (size_t)gr * K + (k0 + cs));
            bf16x4 hv, lv;
            hv.x = (__bf16)v.x; lv.x = (__bf16)(v.x - (float)hv.x);
            hv.y = (__bf16)v.y; lv.y = (__bf16)(v.y - (float)hv.y);
            hv.z = (__bf16)v.z; lv.z = (__bf16)(v.z - (float)hv.z);
            hv.w = (__bf16)v.w; lv.w = (__bf16)(v.w - (float)hv.w);
            *(bf16x4*)&Ah[r][cs] = hv;
            *(bf16x4*)&Al[r][cs] = lv;
        }
#pragma unroll
        for (int it = 0; it < 2; ++it) {
            int r = rs + it * 32;
            int gn = bn + r; if (gn >= N) gn = N - 1;
            float4 v = *(const float4*)(B + (size_t)gn * K + (k0 + cs));
            bf16x4 hv, lv;
            hv.x = (__bf16)v.x; lv.x = (__bf16)(v.x - (float)hv.x);
            hv.y = (__bf16)v.y; lv.y = (__bf16)(v.y - (float)hv.y);
            hv.z = (__bf16)v.z; lv.z = (__bf16)(v.z - (float)hv.z);
            hv.w = (__bf16)v.w; lv.w = (__bf16)(v.w - (float)hv.w);
            *(bf16x4*)&Bh[r][cs] = hv;
            *(bf16x4*)&Bl[r][cs] = lv;
        }
        __syncthreads();

        bf16x8 ah[2], al[2], bh[2], bl[2];
#pragma unroll
        for (int mi = 0; mi < 2; ++mi) {
            int r = wr * 32 + mi * 16 + fr;
            ah[mi] = *(const bf16x8*)&Ah[r][fq * 8];
            al[mi] = *(const bf16x8*)&Al[r][fq * 8];
        }
#pragma unroll
        for (int ni = 0; ni < 2; ++ni) {
            int r = wc * 32 + ni * 16 + fr;
            bh[ni] = *(const bf16x8*)&Bh[r][fq * 8];
            bl[ni] = *(const bf16x8*)&Bl[r][fq * 8];
        }
#pragma unroll
        for (int mi = 0; mi < 2; ++mi)
#pragma unroll
            for (int ni = 0; ni < 2; ++ni) {
                acc[mi][ni] = __builtin_amdgcn_mfma_f32_16x16x32_bf16(ah[mi], bh[ni], acc[mi][ni], 0, 0, 0);
                acc[mi][ni] = __builtin_amdgcn_mfma_f32_16x16x32_bf16(ah[mi], bl[ni], acc[mi][ni], 0, 0, 0);
                acc[mi][ni] = __builtin_amdgcn_mfma_f32_16x16x32_bf16(al[mi], bh[ni], acc[mi][ni], 0, 0, 0);
            }
        __syncthreads();
    }

#pragma unroll
    for (int mi = 0; mi < 2; ++mi)
#pragma unroll
        for (int ni = 0; ni < 2; ++ni) {
            int col = bn + wc * 32 + ni * 16 + fr;
            if (col >= N) continue;
            float bb = bias ? bias[col] : 0.0f;
#pragma unroll
            for (int r = 0; r < 4; ++r) {
                int row = bm + wr * 32 + mi * 16 + fq * 4 + r;
                if (row >= M) continue;
                float v = acc[mi][ni][r] + bb;
                if (doRelu) v = fmaxf(v, 0.0f);
                C[(size_t)row * N + col] = v;
            }
        }
}

// ------------------------------------------------------------------
// Fused GCN aggregate: out = relu(BN(agg + self + bias)) (+ residual)
// agg[n,f] = dinv[n] * sum_{e: dst=n} hw[src_e, f] * dinv[src_e]
// self     = hw[n,f] * dinv[n]^2
__global__ __launch_bounds__(256) void gcn_aggregate(
    const float* __restrict__ hw, const float* __restrict__ res,
    const float* __restrict__ dinv, const unsigned* __restrict__ off,
    const int* __restrict__ csr_src,
    const float* __restrict__ bias, const float* __restrict__ gamma,
    const float* __restrict__ beta, const float* __restrict__ mean,
    const float* __restrict__ var,
    float* __restrict__ hout)
{
    int n = blockIdx.x;
    int f = threadIdx.x;
    float dn = dinv[n];
    unsigned j0 = off[n], j1 = off[n + 1];
    float acc = 0.0f;
    for (unsigned j = j0; j < j1; ++j) {
        int s = csr_src[j];
        acc += hw[(size_t)s * HID + f] * dinv[s];
    }
    acc *= dn;
    acc += hw[(size_t)n * HID + f] * dn * dn;
    acc += bias[f];
    acc = (acc - mean[f]) * rsqrtf(var[f] + BN_EPS) * gamma[f] + beta[f];
    acc = fmaxf(acc, 0.0f);
    if (res) acc += res[(size_t)n * HID + f];
    hout[(size_t)n * HID + f] = acc;
}

// ------------------------------------------------------------------
extern "C" void kernel_launch(void* const* d_in, const int* in_sizes, int n_in,
                              void* d_out, int out_size, void* d_ws, size_t ws_size,
                              hipStream_t stream)
{
    const float* x     = (const float*)d_in[0];
    const int*   eidx  = (const int*)d_in[1];
    const float* in_W  = (const float*)d_in[2];
    const float* in_b  = (const float*)d_in[3];
    const float* gcn_W = (const float*)d_in[4];
    const float* gcn_b = (const float*)d_in[5];
    const float* bn_g  = (const float*)d_in[6];
    const float* bn_be = (const float*)d_in[7];
    const float* bn_m  = (const float*)d_in[8];
    const float* bn_v  = (const float*)d_in[9];
    const float* c1_W  = (const float*)d_in[10];
    const float* c1_b  = (const float*)d_in[11];
    const float* c2_W  = (const float*)d_in[12];
    const float* c2_b  = (const float*)d_in[13];
    const float* c3_W  = (const float*)d_in[14];
    const float* c3_b  = (const float*)d_in[15];
    float* out = (float*)d_out;

    const int NN = NN_NODES;
    const int E  = in_sizes[1] / 2;

    // workspace layout (all 4-byte units)
    float*    hA   = (float*)d_ws;
    float*    hB   = hA + (size_t)NN * HID;
    float*    hw   = hB + (size_t)NN * HID;
    float*    dinv = hw + (size_t)NN * HID;
    unsigned* cnt  = (unsigned*)(dinv + NN);
    unsigned* off  = cnt + NN;
    unsigned* cur  = off + NN + 1;
    unsigned* flag = cur + NN;
    int*      csr  = (int*)(flag + 4);

    // ---- graph prep (CSR + degree norm) ----
    zero_u32<<<(NN + 255) / 256, 256, 0, stream>>>(cnt, NN);
    detect_i64<<<1, 256, 0, stream>>>(eidx, flag);
    count_edges<<<(E + 255) / 256, 256, 0, stream>>>(eidx, flag, cnt, E);
    compute_dinv<<<(NN + 255) / 256, 256, 0, stream>>>(cnt, dinv, NN);
    scan_offsets<<<1, 256, 0, stream>>>(cnt, off, cur, NN);
    fill_csr<<<(E + 255) / 256, 256, 0, stream>>>(eidx, flag, cur, csr, E);

    const int mblk = (NN + BM - 1) / BM;  // 157

    // ---- input projection: hA = relu(x @ in_W^T + in_b) ----
    gemm_bt<<<dim3(mblk, HID / BN), 256, 0, stream>>>(x, in_W, in_b, hA, NN, HID, 2048, 1);

    // ---- 3 GCN layers ----
    float* hcur = hA;
    float* hnext = hB;
    for (int i = 0; i < 3; ++i) {
        gemm_bt<<<dim3(mblk, HID / BN), 256, 0, stream>>>(
            hcur, gcn_W + (size_t)i * HID * HID, nullptr, hw, NN, HID, HID, 0);
        gcn_aggregate<<<NN, HID, 0, stream>>>(
            hw, (i > 0) ? hcur : nullptr, dinv, off, csr,
            gcn_b + i * HID, bn_g + i * HID, bn_be + i * HID,
            bn_m + i * HID, bn_v + i * HID, hnext);
        float* t = hcur; hcur = hnext; hnext = t;
    }

    // ---- classifier ----
    float* c1o = hnext;  // free ping-pong buffer
    float* c2o = hw;
    gemm_bt<<<dim3(mblk, 2), 256, 0, stream>>>(hcur, c1_W, c1_b, c1o, NN, 128, 256, 1);
    gemm_bt<<<dim3(mblk, 1), 256, 0, stream>>>(c1o, c2_W, c2_b, c2o, NN, 64, 128, 1);
    gemm_bt<<<dim3(mblk, 1), 256, 0, stream>>>(c2o, c3_W, c3_b, out, NN, 10, 64, 0);
}